// Round 9
// baseline (225.872 us; speedup 1.0000x reference)
//
#include <hip/hip_runtime.h>

#define N_NODES 100000
#define B_SUB   512
#define NBB     100512              // N_NODES + B_SUB
#define E_N2N   1000000
#define E_SAGE  1200000
#define DD      64

#define RSIZE   16384               // rows per bucket (14-bit local row)
#define NRANGE  7                   // ceil(NBB / RSIZE)
#define NBLK    256                 // k_part blocks per stream
#define NW      4                   // waves per k_part block
#define NPW     1024                // wave-producers per stream (NBLK*NW)
#define CHWN    980                 // edges/wave, n2n  (1024*980 >= 1e6, %4==0)
#define CHWS    1172                // edges/wave, sage (1024*1172 >= 1.2e6, %4==0)
#define CAPWN   272                 // per-(wave,bucket) cap, n2n  (mu 140 + 12.1 sigma)
#define CAPWS   312                 // per-(wave,bucket) cap, sage (mu 167 + 12.2 sigma)
#define NCC     16                  // consumer chunks per bucket (64 producers each)
#define CH_SUBG 392                 // 256*392 >= 1e5
#define FXV     262143.0f           // 18-bit val fixed point
#define MSGB    12500               // 2*N_NODES*16/256
#define QB      128                 // 512 subgraphs / 4 waves per block

// ---------------------------------------------------------------------------
// K1 k_part: single-pass bucketizer + consts. grid = (NBLK, 6), 256 thr.
// PER-WAVE producer regions: offsets live in registers (no LDS atomic / shfl
// dependency chain — R8 lesson). Wave pw owns reg[(sl*7+b)*NPW+pw][CAPW].
//  y 0/1: n2n deg edges -> reg_n2n, pk = (lrow | fx18(val)<<14)
//  y 2/3: sage edges    -> reg_sg,  pk = (lrow | col<<14)  (14+17=31 bits)
//  y 4  : subg weighted histogram -> hs[blk*512 + 0..511]
//  y 5,x 0: cst pipeline (verified R1-8)
// ---------------------------------------------------------------------------
__global__ __launch_bounds__(256)
void k_part(const int* __restrict__ r0, const float* __restrict__ v0,
            const int* __restrict__ r1, const float* __restrict__ v1,
            const int* __restrict__ sr0, const int* __restrict__ sc0,
            const int* __restrict__ sr1, const int* __restrict__ sc1,
            const int* __restrict__ sgr, const float* __restrict__ sgv,
            const float* __restrict__ w_n2l, const float* __restrict__ p_node_conv,
            const float* __restrict__ W_sage,
            unsigned* __restrict__ reg_n2n, unsigned* __restrict__ reg_sg,
            unsigned* __restrict__ cnt_n2n, unsigned* __restrict__ cnt_sg,
            float* __restrict__ hs, float* __restrict__ cst) {
    int s = blockIdx.y, blk = blockIdx.x, tid = threadIdx.x;
    int lane = tid & 63, wv = tid >> 6;

    if (s == 5) {                      // consts (block 0 only)
        if (blk != 0) return;
        __shared__ float sv[DD];
        __shared__ float sw[DD];
        if (tid < DD) {
            float v = fmaxf(w_n2l[tid] + w_n2l[DD + tid], 0.0f);
            float sq = v * v;
#pragma unroll
            for (int o = 32; o; o >>= 1) sq += __shfl_xor(sq, o, 64);
            sv[tid] = v / fmaxf(sqrtf(sq), 1e-12f);
        }
        __syncthreads();
        if (tid < DD) {
            float w = 0.0f;
            for (int k = 0; k < DD; k++) w += sv[k] * p_node_conv[k * DD + tid];
            sw[tid] = w;
        }
        __syncthreads();
        if (tid < DD) {
            float u1 = 0.0f, u2 = 0.0f;
            for (int k = 0; k < DD; k++) {
                float wk = sw[k];
                u1 += wk * W_sage[k * DD + tid];
                u2 += wk * W_sage[(k + DD) * DD + tid];
            }
            cst[tid] = u1;
            cst[DD + tid] = u2;
        }
        return;
    }

    if (s == 4) {                      // subg weighted histogram (512 bins)
        __shared__ float hist[512];
        for (int i = tid; i < 512; i += 256) hist[i] = 0.0f;
        __syncthreads();
        int e0 = blk * CH_SUBG, e1 = min(N_NODES, e0 + CH_SUBG);
        int n4 = (e1 - e0) >> 2;
        const int4* rp = (const int4*)(sgr + e0);
        const float4* vp = (const float4*)(sgv + e0);
        for (int k = tid; k < n4; k += 256) {
            int4 r = rp[k]; float4 v = vp[k];
            atomicAdd(&hist[r.x], v.x);
            atomicAdd(&hist[r.y], v.y);
            atomicAdd(&hist[r.z], v.z);
            atomicAdd(&hist[r.w], v.w);
        }
        __syncthreads();
        for (int i = tid; i < 512; i += 256) hs[blk * 512 + i] = hist[i];
        return;
    }

    const int* rows; const float* fvals = nullptr; const int* cols = nullptr;
    int E, chw, CAPW, sl; unsigned* reg; unsigned* cnt;
    if (s < 2) {
        sl = s; rows = s ? r1 : r0; fvals = s ? v1 : v0;
        E = E_N2N; chw = CHWN; CAPW = CAPWN; reg = reg_n2n; cnt = cnt_n2n;
    } else {
        sl = s - 2; rows = sl ? sr1 : sr0; cols = sl ? sc1 : sc0;
        E = E_SAGE; chw = CHWS; CAPW = CAPWS; reg = reg_sg; cnt = cnt_sg;
    }
    int pw = blk * NW + wv;
    int e0 = pw * chw, e1 = min(E, e0 + chw);
    int n4 = max(0, (e1 - e0) >> 2);   // all boundaries 4-aligned
    const int4* rp = (const int4*)(rows + e0);
    const float4* vp = fvals ? (const float4*)(fvals + e0) : nullptr;
    const int4* cp = cols ? (const int4*)(cols + e0) : nullptr;
    unsigned long long lt = (1ULL << lane) - 1ULL;
    unsigned off[NRANGE];
#pragma unroll
    for (int b = 0; b < NRANGE; b++) off[b] = 0;

    for (int k0 = 0; k0 < n4; k0 += 64) {
        int idx = k0 + lane;
        bool ok = idx < n4;
        int bb[4]; unsigned pk[4];
        if (ok) {
            int4 r = rp[idx];
            if (vp) {
                float4 v = vp[idx];
                bb[0] = r.x >> 14; pk[0] = (r.x & 16383) | ((unsigned)(v.x * FXV + 0.5f) << 14);
                bb[1] = r.y >> 14; pk[1] = (r.y & 16383) | ((unsigned)(v.y * FXV + 0.5f) << 14);
                bb[2] = r.z >> 14; pk[2] = (r.z & 16383) | ((unsigned)(v.z * FXV + 0.5f) << 14);
                bb[3] = r.w >> 14; pk[3] = (r.w & 16383) | ((unsigned)(v.w * FXV + 0.5f) << 14);
            } else {
                int4 c = cp[idx];
                bb[0] = r.x >> 14; pk[0] = (r.x & 16383) | ((unsigned)c.x << 14);
                bb[1] = r.y >> 14; pk[1] = (r.y & 16383) | ((unsigned)c.y << 14);
                bb[2] = r.z >> 14; pk[2] = (r.z & 16383) | ((unsigned)c.z << 14);
                bb[3] = r.w >> 14; pk[3] = (r.w & 16383) | ((unsigned)c.w << 14);
            }
        } else { bb[0] = bb[1] = bb[2] = bb[3] = -1; }

#pragma unroll
        for (int b = 0; b < NRANGE; b++) {
            unsigned long long m0 = __ballot(bb[0] == b);
            unsigned long long m1 = __ballot(bb[1] == b);
            unsigned long long m2 = __ballot(bb[2] == b);
            unsigned long long m3 = __ballot(bb[3] == b);
            unsigned n = __popcll(m0) + __popcll(m1) + __popcll(m2) + __popcll(m3);
            if (n == 0) continue;
            unsigned* dst = reg + ((size_t)((sl * NRANGE + b) * NPW + pw)) * (size_t)CAPW;
            unsigned o = off[b]; off[b] = o + n;
            unsigned p;
            if (bb[0] == b) { p = o + __popcll(m0 & lt); if (p < (unsigned)CAPW) dst[p] = pk[0]; }
            o += __popcll(m0);
            if (bb[1] == b) { p = o + __popcll(m1 & lt); if (p < (unsigned)CAPW) dst[p] = pk[1]; }
            o += __popcll(m1);
            if (bb[2] == b) { p = o + __popcll(m2 & lt); if (p < (unsigned)CAPW) dst[p] = pk[2]; }
            o += __popcll(m2);
            if (bb[3] == b) { p = o + __popcll(m3 & lt); if (p < (unsigned)CAPW) dst[p] = pk[3]; }
        }
    }
    if (lane == 0) {
        unsigned base = (sl * NPW + pw) * 8;
#pragma unroll
        for (int b = 0; b < NRANGE; b++)
            cnt[base + b] = min(off[b], (unsigned)CAPW);
    }
}

// ---------------------------------------------------------------------------
// K2 k_degsum: grid (NCC, 28), 1024 thr, 64 KB f32 LDS (2 blocks/CU).
// slots 0-13:  n2n deg (weighted, from reg_n2n)
// slots 14-27: sage row-count (weight 1, rows from reg_sg low 14 bits)
// Each wave scans 4 of the chunk's 64 producer runs (64 lanes per run).
// ---------------------------------------------------------------------------
__global__ __launch_bounds__(1024)
void k_degsum(const unsigned* __restrict__ reg_n2n, const unsigned* __restrict__ cnt_n2n,
              const unsigned* __restrict__ reg_sg, const unsigned* __restrict__ cnt_sg,
              float* __restrict__ s_deg) {
    __shared__ float acc[RSIZE];
    int tid = threadIdx.x, lane = tid & 63, wv = tid >> 6;
    int slot = blockIdx.y, chunk = blockIdx.x;      // slot = s*7 + b, s in [0,4)
    int s = slot / NRANGE, b = slot % NRANGE;
    float4* a4 = (float4*)acc;
    for (int i = tid; i < RSIZE / 4; i += 1024) a4[i] = make_float4(0.f, 0.f, 0.f, 0.f);
    __syncthreads();
    if (s < 2) {
        for (int r = wv; r < 64; r += 16) {
            int pw = chunk * 64 + r;
            int len = cnt_n2n[(s * NPW + pw) * 8 + b];
            const unsigned* src = reg_n2n + ((size_t)((s * NRANGE + b) * NPW + pw)) * CAPWN;
            for (int i = lane; i < len; i += 64) {
                unsigned pk = src[i];
                atomicAdd(&acc[pk & 16383], (float)(pk >> 14) * (1.0f / FXV));
            }
        }
    } else {
        int sl = s - 2;
        for (int r = wv; r < 64; r += 16) {
            int pw = chunk * 64 + r;
            int len = cnt_sg[(sl * NPW + pw) * 8 + b];
            const unsigned* src = reg_sg + ((size_t)((sl * NRANGE + b) * NPW + pw)) * CAPWS;
            for (int i = lane; i < len; i += 64)
                atomicAdd(&acc[src[i] & 16383], 1.0f);
        }
    }
    __syncthreads();
    float4* dst = (float4*)(s_deg + ((size_t)(slot * NCC + chunk)) * RSIZE);
    for (int i = tid; i < RSIZE / 4; i += 1024) dst[i] = a4[i];
}

// ---------------------------------------------------------------------------
// R1 k_red_deg: d[2*NBB] (deg; virtual rows from hs) and invc = 1/max(cnt,1).
// ---------------------------------------------------------------------------
__global__ __launch_bounds__(1024)
void k_red_deg(const float* __restrict__ s_deg, const float* __restrict__ hs,
               float* __restrict__ d, float* __restrict__ invc) {
    int t = blockIdx.x * 1024 + threadIdx.x;
    if (t >= 2 * NBB) return;
    int l = (t >= NBB) ? 1 : 0;
    int i = t - l * NBB;
    int r = i >> 14, bin = i & 16383;
    float dv = 0.0f;
    if (i < N_NODES) {
        const float* base = s_deg + ((size_t)((l * NRANGE + r) * NCC)) * RSIZE + bin;
#pragma unroll
        for (int c = 0; c < NCC; c++) dv += base[(size_t)c * RSIZE];
    } else {
        int bs = i - N_NODES;
        for (int pb = 0; pb < NBLK; pb++) dv += hs[pb * 512 + bs];
    }
    d[t] = dv;
    float cv = 0.0f;
    const float* cb = s_deg + ((size_t)(((2 + l) * NRANGE + r) * NCC)) * RSIZE + bin;
#pragma unroll
    for (int c = 0; c < NCC; c++) cv += cb[(size_t)c * RSIZE];
    invc[t] = 1.0f / fmaxf(cv, 1.0f);
}

// ---------------------------------------------------------------------------
// K3 k_sagesum: f32 bins (64 KB LDS -> 2 blocks/CU, full 32 waves).
// grid (NCC, 14); gathers d[col] (L2-hot 800 KB) into LDS f32 bins.
// ---------------------------------------------------------------------------
__global__ __launch_bounds__(1024)
void k_sagesum(const unsigned* __restrict__ reg_sg, const unsigned* __restrict__ cnt_sg,
               const float* __restrict__ d, float* __restrict__ s_sg) {
    __shared__ float acc[RSIZE];
    int tid = threadIdx.x, lane = tid & 63, wv = tid >> 6;
    int slot = blockIdx.y, chunk = blockIdx.x;      // slot = l*7 + b
    int l = slot / NRANGE, b = slot % NRANGE;
    float4* a4 = (float4*)acc;
    for (int i = tid; i < RSIZE / 4; i += 1024) a4[i] = make_float4(0.f, 0.f, 0.f, 0.f);
    __syncthreads();
    const float* dl = d + (size_t)l * NBB;
    for (int r = wv; r < 64; r += 16) {
        int pw = chunk * 64 + r;
        int len = cnt_sg[(l * NPW + pw) * 8 + b];
        const unsigned* src = reg_sg + ((size_t)((l * NRANGE + b) * NPW + pw)) * CAPWS;
        for (int i = lane; i < len; i += 64) {
            unsigned pk = src[i];
            atomicAdd(&acc[pk & 16383], dl[pk >> 14]);
        }
    }
    __syncthreads();
    float4* dst = (float4*)(s_sg + ((size_t)(slot * NCC + chunk)) * RSIZE);
    for (int i = tid; i < RSIZE / 4; i += 1024) dst[i] = a4[i];
}

// ---------------------------------------------------------------------------
// helper: per-row normalized msg value for lane j (=lane); wave-uniform row.
// ---------------------------------------------------------------------------
__device__ __forceinline__ float row_val(int l, int i,
                                         const float* __restrict__ s_sg,
                                         const float* __restrict__ d,
                                         const float* __restrict__ invc,
                                         const float* __restrict__ cst, int lane) {
    int slot = l * NRANGE + (i >> 14), bin = i & 16383;
    const float* sb = s_sg + (size_t)slot * NCC * RSIZE + bin;
    float v = sb[(size_t)(lane & 15) * RSIZE];
    v += __shfl_xor(v, 1, 16);
    v += __shfl_xor(v, 2, 16);
    v += __shfl_xor(v, 4, 16);
    v += __shfl_xor(v, 8, 16);
    int t = l * NBB + i;
    float a = v * invc[t];
    float dv = d[t];
    float val = fmaxf(dv * cst[lane] + a * cst[DD + lane], 0.0f);
    float sq = val * val;
#pragma unroll
    for (int o = 32; o; o >>= 1) sq += __shfl_xor(sq, o, 64);
    return val * __frsqrt_rn(fmaxf(sq, 1e-24f));
}

// ---------------------------------------------------------------------------
// K4 k_msg (+q head): blocks [0,MSGB): 16 rows/block, 16 lanes/row; f32
// slice butterfly (width 16) -> a; relu/normalize; float4 store of cur.
// blocks [MSGB,MSGB+QB): q head, 4 waves/block, rows recomputed via row_val.
// ---------------------------------------------------------------------------
__global__ __launch_bounds__(256)
void k_msg(const float* __restrict__ s_sg, const float* __restrict__ d,
           const float* __restrict__ invc, const float* __restrict__ cst,
           float* __restrict__ out,
           const int* __restrict__ act_col, const float* __restrict__ aux,
           const float* __restrict__ cross, const float* __restrict__ h1w,
           const float* __restrict__ h2w) {
    int tid = threadIdx.x;
    if (blockIdx.x < MSGB) {
        unsigned idx = blockIdx.x * 256 + tid;
        unsigned row2 = idx >> 4;           // 0 .. 2*N_NODES-1
        int q = idx & 15, j0 = q << 2;
        int l = row2 >= (unsigned)N_NODES;
        int i = (int)row2 - l * N_NODES;
        int slot = l * NRANGE + (i >> 14), bin = i & 16383;
        const float* sb = s_sg + (size_t)slot * NCC * RSIZE + bin;
        float v = sb[(size_t)q * RSIZE];
        v += __shfl_xor(v, 1, 16);
        v += __shfl_xor(v, 2, 16);
        v += __shfl_xor(v, 4, 16);
        v += __shfl_xor(v, 8, 16);
        int t = l * NBB + i;
        float a = v * invc[t];
        float dv = d[t];
        float4 u1 = *(const float4*)(cst + j0);
        float4 u2 = *(const float4*)(cst + DD + j0);
        float4 r;
        r.x = fmaxf(dv * u1.x + a * u2.x, 0.0f);
        r.y = fmaxf(dv * u1.y + a * u2.y, 0.0f);
        r.z = fmaxf(dv * u1.z + a * u2.z, 0.0f);
        r.w = fmaxf(dv * u1.w + a * u2.w, 0.0f);
        float sq = r.x * r.x + r.y * r.y + r.z * r.z + r.w * r.w;
        sq += __shfl_xor(sq, 1, 16);
        sq += __shfl_xor(sq, 2, 16);
        sq += __shfl_xor(sq, 4, 16);
        sq += __shfl_xor(sq, 8, 16);
        float iv = __frsqrt_rn(fmaxf(sq, 1e-24f));
        r.x *= iv; r.y *= iv; r.z *= iv; r.w *= iv;
        *(float4*)(out + 512 + (size_t)row2 * DD + j0) = r;
        return;
    }
    // ---- q head: 4 waves per block, one subgraph b per wave ----
    __shared__ float esa[4][DD];
    int wv = tid >> 6, lane = tid & 63;
    int b = (blockIdx.x - MSGB) * 4 + wv;   // 0..511
    float qacc = 0.0f;
    int ac = act_col[b];
#pragma unroll
    for (int l = 0; l < 2; l++) {
        float y = row_val(l, N_NODES + b, s_sg, d, invc, cst, lane);
        float s = y * cross[lane];
#pragma unroll
        for (int o = 32; o; o >>= 1) s += __shfl_xor(s, o, 64);
        float ae = row_val(l, ac, s_sg, d, invc, cst, lane);
        esa[wv][lane] = ae * s;             // wave-local; no barrier needed
        float contrib = 0.0f;
        if (lane < 32) {
            float h = 0.0f;
            for (int k = 0; k < DD; k++) h += esa[wv][k] * h1w[k * 32 + lane];
            h = fmaxf(h, 0.0f);
            contrib = h * h2w[lane];
        } else if (lane < 36) {
            contrib = aux[(b * 2 + l) * 4 + (lane - 32)] * h2w[lane];
        }
#pragma unroll
        for (int o = 32; o; o >>= 1) contrib += __shfl_xor(contrib, o, 64);
        qacc += contrib;
    }
    if (lane == 0) out[b] = qacc;
}

extern "C" void kernel_launch(void* const* d_in, const int* in_sizes, int n_in,
                              void* d_out, int out_size, void* d_ws, size_t ws_size,
                              hipStream_t stream) {
    const int*   n2n0_row  = (const int*)d_in[0];
    const float* n2n0_val  = (const float*)d_in[2];
    const int*   n2n1_row  = (const int*)d_in[3];
    const float* n2n1_val  = (const float*)d_in[5];
    const int*   subg_row  = (const int*)d_in[6];
    const float* subg_val  = (const float*)d_in[8];
    const int*   act_col   = (const int*)d_in[9];
    const int*   sage0_row = (const int*)d_in[10];
    const int*   sage0_col = (const int*)d_in[11];
    const int*   sage1_row = (const int*)d_in[12];
    const int*   sage1_col = (const int*)d_in[13];
    const float* aux_input = (const float*)d_in[14];
    const float* w_n2l     = (const float*)d_in[15];
    const float* p_node    = (const float*)d_in[16];
    const float* W_sage    = (const float*)d_in[17];
    const float* cross     = (const float*)d_in[18];
    const float* h1_weight = (const float*)d_in[19];
    const float* h2_weight = (const float*)d_in[20];

    // All scratch in d_ws; everything producer-written (capped-length reads
    // via cnt arrays) -> no zeroing anywhere.
    float* wb = (float*)d_ws;
    float*    s_deg   = wb;                                      // 28*NCC*RSIZE f32
    float*    s_sg    = s_deg + (size_t)28 * NCC * RSIZE;        // 14*NCC*RSIZE f32
    unsigned* reg_n2n = (unsigned*)(s_sg + (size_t)14 * NCC * RSIZE);
    unsigned* reg_sg  = reg_n2n + (size_t)2 * NRANGE * NPW * CAPWN;
    unsigned* cnt_n2n = reg_sg + (size_t)2 * NRANGE * NPW * CAPWS;
    unsigned* cnt_sg  = cnt_n2n + 2 * NPW * 8;
    float*    hs      = (float*)(cnt_sg + 2 * NPW * 8);          // NBLK*512 f32
    float*    d       = hs + NBLK * 512;                         // 2*NBB
    float*    invc    = d + 2 * NBB;                             // 2*NBB
    float*    cst     = invc + 2 * NBB;                          // 128

    k_part<<<dim3(NBLK, 6), 256, 0, stream>>>(
        n2n0_row, n2n0_val, n2n1_row, n2n1_val,
        sage0_row, sage0_col, sage1_row, sage1_col,
        subg_row, subg_val, w_n2l, p_node, W_sage,
        reg_n2n, reg_sg, cnt_n2n, cnt_sg, hs, cst);

    k_degsum<<<dim3(NCC, 28), 1024, 0, stream>>>(reg_n2n, cnt_n2n,
                                                 reg_sg, cnt_sg, s_deg);

    k_red_deg<<<(2 * NBB + 1023) / 1024, 1024, 0, stream>>>(s_deg, hs, d, invc);

    k_sagesum<<<dim3(NCC, 14), 1024, 0, stream>>>(reg_sg, cnt_sg, d, s_sg);

    float* out = (float*)d_out;
    k_msg<<<MSGB + QB, 256, 0, stream>>>(s_sg, d, invc, cst, out,
                                         act_col, aux_input, cross,
                                         h1_weight, h2_weight);
}

// Round 10
// 215.508 us; speedup vs baseline: 1.0481x; 1.0481x over previous
//
#include <hip/hip_runtime.h>

#define N_NODES 100000
#define B_SUB   512
#define NBB     100512              // N_NODES + B_SUB
#define E_N2N   1000000
#define E_SAGE  1200000
#define DD      64

#define RSIZE   16384               // rows per bucket (14-bit local row)
#define NRANGE  7                   // ceil(NBB / RSIZE)
#define NBLK    256                 // producer blocks per stream
#define CAPN    832                 // per-(block,bucket) cap, n2n  (mu 558 + ~12 sigma; verified R5-R8)
#define CAPS    992                 // per-(block,bucket) cap, sage (mu 670 + ~13 sigma; verified R5-R8)
#define NCC     16                  // consumer chunks per bucket (NBLK/NCC=16 producers each)
#define CH_N2N  3908                // 256*3908 >= 1e6, multiple of 4
#define CH_SAGE 4688                // 256*4688 >= 1.2e6
#define CH_SUBG 392                 // 256*392  >= 1e5
#define FXV     262143.0f           // 18-bit val fixed point
#define FXS     8388608.0f          // 2^23 sum fixed point
#define FXMASK  0xFFFFFFFFFFULL
#define MSGB    12500               // 2*N_NODES*16/256
#define QB      128                 // 512 subgraphs / 4 waves per block

// ---------------------------------------------------------------------------
// K1 k_part: single-pass bucketizer + consts. grid = (NBLK, 6), 256 thr.
// R10 change (single mechanism): 16 edges/lane per allocation round — the
// serialized per-bucket LDS-atomic->shfl chain runs once per 4096 edges
// instead of once per 1024 (R4 evidence: k_part latency-bound, VALUBusy 18%).
//  y 0/1: n2n deg edges -> reg_n2n, pk = (lrow | fx18(val)<<14)
//  y 2/3: sage edges    -> reg_sg,  pk = (lrow | col<<14)   (14+17=31 bits)
//  y 4  : subg weighted histogram -> hs[blk*512 + 0..511]
//  y 5,x 0: cst pipeline (verified R1-8)
// ---------------------------------------------------------------------------
__global__ __launch_bounds__(256)
void k_part(const int* __restrict__ r0, const float* __restrict__ v0,
            const int* __restrict__ r1, const float* __restrict__ v1,
            const int* __restrict__ sr0, const int* __restrict__ sc0,
            const int* __restrict__ sr1, const int* __restrict__ sc1,
            const int* __restrict__ sgr, const float* __restrict__ sgv,
            const float* __restrict__ w_n2l, const float* __restrict__ p_node_conv,
            const float* __restrict__ W_sage,
            unsigned* __restrict__ reg_n2n, unsigned* __restrict__ reg_sg,
            unsigned* __restrict__ cnt_n2n, unsigned* __restrict__ cnt_sg,
            float* __restrict__ hs, float* __restrict__ cst) {
    int s = blockIdx.y, blk = blockIdx.x, tid = threadIdx.x;
    int lane = tid & 63;

    if (s == 5) {                      // consts (block 0 only)
        if (blk != 0) return;
        __shared__ float sv[DD];
        __shared__ float sw[DD];
        if (tid < DD) {
            float v = fmaxf(w_n2l[tid] + w_n2l[DD + tid], 0.0f);
            float sq = v * v;
#pragma unroll
            for (int o = 32; o; o >>= 1) sq += __shfl_xor(sq, o, 64);
            sv[tid] = v / fmaxf(sqrtf(sq), 1e-12f);
        }
        __syncthreads();
        if (tid < DD) {
            float w = 0.0f;
            for (int k = 0; k < DD; k++) w += sv[k] * p_node_conv[k * DD + tid];
            sw[tid] = w;
        }
        __syncthreads();
        if (tid < DD) {
            float u1 = 0.0f, u2 = 0.0f;
            for (int k = 0; k < DD; k++) {
                float wk = sw[k];
                u1 += wk * W_sage[k * DD + tid];
                u2 += wk * W_sage[(k + DD) * DD + tid];
            }
            cst[tid] = u1;
            cst[DD + tid] = u2;
        }
        return;
    }

    if (s == 4) {                      // subg weighted histogram (512 bins)
        __shared__ float hist[512];
        for (int i = tid; i < 512; i += 256) hist[i] = 0.0f;
        __syncthreads();
        int e0 = blk * CH_SUBG, e1 = min(N_NODES, e0 + CH_SUBG);
        int n4 = (e1 - e0) >> 2;
        const int4* rp = (const int4*)(sgr + e0);
        const float4* vp = (const float4*)(sgv + e0);
        for (int k = tid; k < n4; k += 256) {
            int4 r = rp[k]; float4 v = vp[k];
            atomicAdd(&hist[r.x], v.x);
            atomicAdd(&hist[r.y], v.y);
            atomicAdd(&hist[r.z], v.z);
            atomicAdd(&hist[r.w], v.w);
        }
        __syncthreads();
        for (int i = tid; i < 512; i += 256) hs[blk * 512 + i] = hist[i];
        return;
    }

    __shared__ unsigned lcnt[NRANGE];
    if (tid < NRANGE) lcnt[tid] = 0;
    __syncthreads();

    const int* rows; const float* fvals = nullptr; const int* cols = nullptr;
    int E, CH, CAP, sl; unsigned* reg; unsigned* cnt;
    if (s < 2) {
        sl = s; rows = s ? r1 : r0; fvals = s ? v1 : v0;
        E = E_N2N; CH = CH_N2N; CAP = CAPN; reg = reg_n2n; cnt = cnt_n2n;
    } else {
        sl = s - 2; rows = sl ? sr1 : sr0; cols = sl ? sc1 : sc0;
        E = E_SAGE; CH = CH_SAGE; CAP = CAPS; reg = reg_sg; cnt = cnt_sg;
    }
    int e0 = blk * CH, e1 = min(E, e0 + CH);
    int n4 = (e1 - e0) >> 2;           // chunk boundaries all 4-aligned
    const int4* rp = (const int4*)(rows + e0);
    const float4* vp = fvals ? (const float4*)(fvals + e0) : nullptr;
    const int4* cp = cols ? (const int4*)(cols + e0) : nullptr;
    unsigned long long lt = (1ULL << lane) - 1ULL;
    unsigned* regbase = reg + ((size_t)(sl * NRANGE) * NBLK + blk) * (size_t)CAP;
    size_t bstride = (size_t)NBLK * (size_t)CAP;

    for (int k0 = 0; k0 < n4; k0 += 1024) {      // 16 edges/lane per round
        int bb[16]; unsigned pk[16];
#pragma unroll
        for (int j = 0; j < 4; j++) {
            int idx = k0 + j * 256 + tid;
            if (idx < n4) {
                int4 r = rp[idx];
                if (vp) {
                    float4 v = vp[idx];
                    bb[4*j+0] = r.x >> 14; pk[4*j+0] = (r.x & 16383) | ((unsigned)(v.x * FXV + 0.5f) << 14);
                    bb[4*j+1] = r.y >> 14; pk[4*j+1] = (r.y & 16383) | ((unsigned)(v.y * FXV + 0.5f) << 14);
                    bb[4*j+2] = r.z >> 14; pk[4*j+2] = (r.z & 16383) | ((unsigned)(v.z * FXV + 0.5f) << 14);
                    bb[4*j+3] = r.w >> 14; pk[4*j+3] = (r.w & 16383) | ((unsigned)(v.w * FXV + 0.5f) << 14);
                } else {
                    int4 c = cp[idx];
                    bb[4*j+0] = r.x >> 14; pk[4*j+0] = (r.x & 16383) | ((unsigned)c.x << 14);
                    bb[4*j+1] = r.y >> 14; pk[4*j+1] = (r.y & 16383) | ((unsigned)c.y << 14);
                    bb[4*j+2] = r.z >> 14; pk[4*j+2] = (r.z & 16383) | ((unsigned)c.z << 14);
                    bb[4*j+3] = r.w >> 14; pk[4*j+3] = (r.w & 16383) | ((unsigned)c.w << 14);
                }
            } else {
                bb[4*j+0] = bb[4*j+1] = bb[4*j+2] = bb[4*j+3] = -1;
            }
        }

        for (int b = 0; b < NRANGE; b++) {
            unsigned long long m[16];
            unsigned n = 0;
#pragma unroll
            for (int j = 0; j < 16; j++) {
                m[j] = __ballot(bb[j] == b);
                n += (unsigned)__popcll(m[j]);
            }
            if (n == 0) continue;
            unsigned base = 0;
            if (lane == 0) base = atomicAdd(&lcnt[b], n);
            base = (unsigned)__shfl((int)base, 0, 64);
            unsigned* dst = regbase + (size_t)b * bstride;
            unsigned o = base;
#pragma unroll
            for (int j = 0; j < 16; j++) {
                if (bb[j] == b) {
                    unsigned p = o + (unsigned)__popcll(m[j] & lt);
                    if (p < (unsigned)CAP) dst[p] = pk[j];
                }
                o += (unsigned)__popcll(m[j]);
            }
        }
    }
    __syncthreads();
    if (tid < NRANGE) cnt[(sl * NBLK + blk) * 8 + tid] = min(lcnt[tid], (unsigned)CAP);
}

// ---------------------------------------------------------------------------
// K2 k_degsum: R8 body. grid = (NCC, 14), 512 thr, 64 KB LDS.
// ---------------------------------------------------------------------------
__global__ __launch_bounds__(512)
void k_degsum(const unsigned* __restrict__ reg, const unsigned* __restrict__ cnt,
              float* __restrict__ s_deg) {
    __shared__ float acc[RSIZE];
    int tid = threadIdx.x;
    int slot = blockIdx.y, chunk = blockIdx.x;      // slot = s*7 + b
    int s = slot / NRANGE, b = slot % NRANGE;
    for (int i = tid; i < RSIZE; i += 512) acc[i] = 0.0f;
    __syncthreads();
    for (int pb = chunk * 16; pb < chunk * 16 + 16; pb++) {
        int len = cnt[(s * NBLK + pb) * 8 + b];
        const unsigned* src = reg + ((size_t)((s * NRANGE + b) * NBLK + pb)) * CAPN;
        for (int i = tid; i < len; i += 512) {
            unsigned pk = src[i];
            atomicAdd(&acc[pk & 16383], (float)(pk >> 14) * (1.0f / FXV));
        }
    }
    __syncthreads();
    float* dst = s_deg + ((size_t)(slot * NCC + chunk)) * RSIZE;
    for (int i = tid; i < RSIZE; i += 512) dst[i] = acc[i];
}

// ---------------------------------------------------------------------------
// R1 k_red_deg: R8 body. d[2*NBB] from deg slices + hs.
// ---------------------------------------------------------------------------
__global__ void k_red_deg(const float* __restrict__ s_deg,
                          const float* __restrict__ hs, float* __restrict__ d) {
    int t = blockIdx.x * blockDim.x + threadIdx.x;
    if (t >= 2 * NBB) return;
    int l = (t >= NBB) ? 1 : 0;
    int i = t - l * NBB;
    float sv = 0.0f;
    if (i < N_NODES) {
        int slot = l * NRANGE + (i >> 14), bin = i & 16383;
        const float* base = s_deg + (size_t)slot * NCC * RSIZE + bin;
#pragma unroll
        for (int c = 0; c < NCC; c++) sv += base[(size_t)c * RSIZE];
    } else {
        int bsub = i - N_NODES;
        for (int pb = 0; pb < NBLK; pb++) sv += hs[pb * 512 + bsub];
    }
    d[t] = sv;
}

// ---------------------------------------------------------------------------
// K3 k_sagesum: R8 body. u64 LDS bins (cnt<<40 | fx23 sum).
// grid = (NCC, 14), 1024 thr, 128 KB LDS.
// ---------------------------------------------------------------------------
__global__ __launch_bounds__(1024)
void k_sagesum(const unsigned* __restrict__ reg, const unsigned* __restrict__ cnt,
               const float* __restrict__ d, unsigned long long* __restrict__ s_sage) {
    __shared__ unsigned long long acc[RSIZE];   // 128 KB
    int tid = threadIdx.x;
    int slot = blockIdx.y, chunk = blockIdx.x;  // slot = l*7 + b
    int l = slot / NRANGE, b = slot % NRANGE;
    for (int i = tid; i < RSIZE; i += 1024) acc[i] = 0ULL;
    __syncthreads();
    const float* dl = d + (size_t)l * NBB;
    for (int pb = chunk * 16; pb < chunk * 16 + 16; pb++) {
        int len = cnt[(l * NBLK + pb) * 8 + b];
        const unsigned* src = reg + ((size_t)((l * NRANGE + b) * NBLK + pb)) * CAPS;
        for (int i = tid; i < len; i += 1024) {
            unsigned pk = src[i];
            float f = dl[pk >> 14];
            unsigned long long q = (1ULL << 40) |
                (unsigned long long)(f * FXS + 0.5f);
            atomicAdd(&acc[pk & 16383], q);
        }
    }
    __syncthreads();
    unsigned long long* dst = s_sage + ((size_t)(slot * NCC + chunk)) * RSIZE;
    for (int i = tid; i < RSIZE; i += 1024) dst[i] = acc[i];
}

// ---------------------------------------------------------------------------
// helper: full per-row normalized msg value for this lane's j (=lane),
// recomputed from slices + d + cst. Wave-uniform row; all 64 lanes join.
// ---------------------------------------------------------------------------
__device__ __forceinline__ float row_val(int l, int i,
                                         const unsigned long long* __restrict__ s_sage,
                                         const float* __restrict__ d,
                                         const float* __restrict__ cst, int lane) {
    int slot = l * NRANGE + (i >> 14), bin = i & 16383;
    const unsigned long long* sb = s_sage + (size_t)slot * NCC * RSIZE + bin;
    unsigned long long v = sb[(size_t)(lane & 15) * RSIZE];
    v += __shfl_xor(v, 1, 16);
    v += __shfl_xor(v, 2, 16);
    v += __shfl_xor(v, 4, 16);
    v += __shfl_xor(v, 8, 16);
    float cntv = (float)(unsigned)(v >> 40);
    float sum = (float)(v & FXMASK) * (1.0f / FXS);
    float a = sum / fmaxf(cntv, 1.0f);
    float dv = d[l * NBB + i];
    float val = fmaxf(dv * cst[lane] + a * cst[DD + lane], 0.0f);
    float sq = val * val;
#pragma unroll
    for (int o = 32; o; o >>= 1) sq += __shfl_xor(sq, o, 64);
    return val * __frsqrt_rn(fmaxf(sq, 1e-24f));
}

// ---------------------------------------------------------------------------
// K4 k_msg (+inline rowscale +q head): R8 body.
// ---------------------------------------------------------------------------
__global__ __launch_bounds__(256)
void k_msg(const unsigned long long* __restrict__ s_sage,
           const float* __restrict__ d, const float* __restrict__ cst,
           float* __restrict__ out,
           const int* __restrict__ act_col, const float* __restrict__ aux,
           const float* __restrict__ cross, const float* __restrict__ h1w,
           const float* __restrict__ h2w) {
    int tid = threadIdx.x;
    if (blockIdx.x < MSGB) {
        unsigned idx = blockIdx.x * 256 + tid;
        unsigned row2 = idx >> 4;           // 0 .. 2*N_NODES-1
        int q = idx & 15, j0 = q << 2;
        int l = row2 >= (unsigned)N_NODES;
        int i = (int)row2 - l * N_NODES;
        int slot = l * NRANGE + (i >> 14), bin = i & 16383;
        const unsigned long long* sb = s_sage + (size_t)slot * NCC * RSIZE + bin;
        unsigned long long v = sb[(size_t)q * RSIZE];
        v += __shfl_xor(v, 1, 16);
        v += __shfl_xor(v, 2, 16);
        v += __shfl_xor(v, 4, 16);
        v += __shfl_xor(v, 8, 16);
        float cntv = (float)(unsigned)(v >> 40);
        float sum = (float)(v & FXMASK) * (1.0f / FXS);
        float a = sum / fmaxf(cntv, 1.0f);
        float dv = d[l * NBB + i];
        float4 u1 = *(const float4*)(cst + j0);
        float4 u2 = *(const float4*)(cst + DD + j0);
        float4 r;
        r.x = fmaxf(dv * u1.x + a * u2.x, 0.0f);
        r.y = fmaxf(dv * u1.y + a * u2.y, 0.0f);
        r.z = fmaxf(dv * u1.z + a * u2.z, 0.0f);
        r.w = fmaxf(dv * u1.w + a * u2.w, 0.0f);
        float sq = r.x * r.x + r.y * r.y + r.z * r.z + r.w * r.w;
        sq += __shfl_xor(sq, 1, 16);
        sq += __shfl_xor(sq, 2, 16);
        sq += __shfl_xor(sq, 4, 16);
        sq += __shfl_xor(sq, 8, 16);
        float iv = __frsqrt_rn(fmaxf(sq, 1e-24f));
        r.x *= iv; r.y *= iv; r.z *= iv; r.w *= iv;
        *(float4*)(out + 512 + (size_t)row2 * DD + j0) = r;
        return;
    }
    // ---- q head: 4 waves per block, one subgraph b per wave ----
    __shared__ float esa[4][DD];
    int wv = tid >> 6, lane = tid & 63;
    int b = (blockIdx.x - MSGB) * 4 + wv;   // 0..511
    float qacc = 0.0f;
    int ac = act_col[b];
#pragma unroll
    for (int l = 0; l < 2; l++) {
        float y = row_val(l, N_NODES + b, s_sage, d, cst, lane);
        float s = y * cross[lane];
#pragma unroll
        for (int o = 32; o; o >>= 1) s += __shfl_xor(s, o, 64);
        float ae = row_val(l, ac, s_sage, d, cst, lane);
        esa[wv][lane] = ae * s;             // wave-local; no barrier needed
        float contrib = 0.0f;
        if (lane < 32) {
            float h = 0.0f;
            for (int k = 0; k < DD; k++) h += esa[wv][k] * h1w[k * 32 + lane];
            h = fmaxf(h, 0.0f);
            contrib = h * h2w[lane];
        } else if (lane < 36) {
            contrib = aux[(b * 2 + l) * 4 + (lane - 32)] * h2w[lane];
        }
#pragma unroll
        for (int o = 32; o; o >>= 1) contrib += __shfl_xor(contrib, o, 64);
        qacc += contrib;
    }
    if (lane == 0) out[b] = qacc;
}

extern "C" void kernel_launch(void* const* d_in, const int* in_sizes, int n_in,
                              void* d_out, int out_size, void* d_ws, size_t ws_size,
                              hipStream_t stream) {
    const int*   n2n0_row  = (const int*)d_in[0];
    const float* n2n0_val  = (const float*)d_in[2];
    const int*   n2n1_row  = (const int*)d_in[3];
    const float* n2n1_val  = (const float*)d_in[5];
    const int*   subg_row  = (const int*)d_in[6];
    const float* subg_val  = (const float*)d_in[8];
    const int*   act_col   = (const int*)d_in[9];
    const int*   sage0_row = (const int*)d_in[10];
    const int*   sage0_col = (const int*)d_in[11];
    const int*   sage1_row = (const int*)d_in[12];
    const int*   sage1_col = (const int*)d_in[13];
    const float* aux_input = (const float*)d_in[14];
    const float* w_n2l     = (const float*)d_in[15];
    const float* p_node    = (const float*)d_in[16];
    const float* W_sage    = (const float*)d_in[17];
    const float* cross     = (const float*)d_in[18];
    const float* h1_weight = (const float*)d_in[19];
    const float* h2_weight = (const float*)d_in[20];

    // All scratch in d_ws; u64 array first for 8B alignment; everything is
    // producer-written (capped-length reads via cnt arrays) -> no zeroing.
    char* wb = (char*)d_ws;
    unsigned long long* s_sage = (unsigned long long*)wb;        // 14*NCC*RSIZE u64
    float* s_deg  = (float*)(s_sage + (size_t)14 * NCC * RSIZE); // 14*NCC*RSIZE f32
    unsigned* reg_n2n = (unsigned*)(s_deg + (size_t)14 * NCC * RSIZE);
    unsigned* reg_sg  = reg_n2n + (size_t)2 * NRANGE * NBLK * CAPN;
    unsigned* cnt_n2n = reg_sg + (size_t)2 * NRANGE * NBLK * CAPS;
    unsigned* cnt_sg  = cnt_n2n + 2 * NBLK * 8;
    float*    hs      = (float*)(cnt_sg + 2 * NBLK * 8);         // NBLK*512 f32
    float*    d       = hs + NBLK * 512;                         // 2*NBB
    float*    cst     = d + 2 * NBB;                             // 128

    k_part<<<dim3(NBLK, 6), 256, 0, stream>>>(
        n2n0_row, n2n0_val, n2n1_row, n2n1_val,
        sage0_row, sage0_col, sage1_row, sage1_col,
        subg_row, subg_val, w_n2l, p_node, W_sage,
        reg_n2n, reg_sg, cnt_n2n, cnt_sg, hs, cst);

    k_degsum<<<dim3(NCC, 14), 512, 0, stream>>>(reg_n2n, cnt_n2n, s_deg);

    k_red_deg<<<(2 * NBB + 255) / 256, 256, 0, stream>>>(s_deg, hs, d);

    k_sagesum<<<dim3(NCC, 14), 1024, 0, stream>>>(reg_sg, cnt_sg, d, s_sage);

    float* out = (float*)d_out;
    k_msg<<<MSGB + QB, 256, 0, stream>>>(s_sage, d, cst, out,
                                         act_col, aux_input, cross,
                                         h1_weight, h2_weight);
}